// Round 1
// baseline (409.334 us; speedup 1.0000x reference)
//
#include <hip/hip_runtime.h>
#include <stdint.h>

#define LEAKY(x) ((x) > 0.f ? (x) : 0.01f*(x))

typedef __attribute__((ext_vector_type(8))) short bf16x8;
typedef __attribute__((ext_vector_type(4))) float f32x4;

__device__ __forceinline__ unsigned short f2bf(float x){
  unsigned u = __float_as_uint(x);
  u += 0x7FFFu + ((u >> 16) & 1u);
  return (unsigned short)(u >> 16);
}
__device__ __forceinline__ void fma4(float4& a, float s, const float4& w){
  a.x = fmaf(s, w.x, a.x); a.y = fmaf(s, w.y, a.y);
  a.z = fmaf(s, w.z, a.z); a.w = fmaf(s, w.w, a.w);
}
__device__ __forceinline__ float dot16(const float* __restrict__ xn, const float* wg, float a){
  float4 x0 = *(const float4*)(xn);
  float4 x1 = *(const float4*)(xn+4);
  float4 x2 = *(const float4*)(xn+8);
  float4 x3 = *(const float4*)(xn+12);
  a = fmaf(x0.x, wg[0], a);  a = fmaf(x0.y, wg[1], a);  a = fmaf(x0.z, wg[2], a);  a = fmaf(x0.w, wg[3], a);
  a = fmaf(x1.x, wg[4], a);  a = fmaf(x1.y, wg[5], a);  a = fmaf(x1.z, wg[6], a);  a = fmaf(x1.w, wg[7], a);
  a = fmaf(x2.x, wg[8], a);  a = fmaf(x2.y, wg[9], a);  a = fmaf(x2.z, wg[10], a); a = fmaf(x2.w, wg[11], a);
  a = fmaf(x3.x, wg[12], a); a = fmaf(x3.y, wg[13], a); a = fmaf(x3.z, wg[14], a); a = fmaf(x3.w, wg[15], a);
  return a;
}

// edge_enc[b,j,f] = sum_i leaky(edge[b,i,j,:]@We + be) * adj[b,i,j]
__global__ __launch_bounds__(256) void k_edge(const float* __restrict__ inp,
                                              const float* __restrict__ We,
                                              const float* __restrict__ be,
                                              float* __restrict__ edge_enc){
  int b = blockIdx.x >> 3, jg = blockIdx.x & 7;
  int t = threadIdx.x;
  int j = jg*16 + (t >> 4), f = t & 15;
  const float* base = inp + (size_t)b*30*128*389;
  float w0 = We[f], w1 = We[16+f], bf = be[f];
  float acc = 0.f;
  for (int i = 0; i < 128; ++i){
    const float* row = base + i*389;
    float adjv = row[j];
    float2 e = *(const float2*)(row + 128 + 2*j);
    float v = fmaf(e.x, w0, fmaf(e.y, w1, bf));
    v = LEAKY(v);
    acc = fmaf(v, adjv, acc);
  }
  edge_enc[b*2048 + j*16 + f] = acc;
}

// Per-b: diag=1, two rounds of symmetric degree normalization -> bf16 A1,A2
__global__ __launch_bounds__(256) void k_prep(const float* __restrict__ inp,
                                              unsigned short* __restrict__ A1b,
                                              unsigned short* __restrict__ A2b){
  __shared__ float As[128*129];
  __shared__ float ps[256];
  __shared__ float dg[128];
  int b = blockIdx.x, t = threadIdx.x;
  const float* base = inp + (size_t)b*30*128*389;
  for (int idx = t; idx < 16384; idx += 256){
    int n = idx >> 7, m = idx & 127;
    As[n*129 + m] = base[n*389 + m];
  }
  __syncthreads();
  if (t < 128) As[t*129 + t] = 1.0f;
  __syncthreads();
  for (int pass = 0; pass < 2; ++pass){
    int n = t >> 1, h = t & 1;
    float s = 0.f;
    for (int m = h*64; m < h*64 + 64; ++m) s += As[n*129 + m];
    ps[t] = s;
    __syncthreads();
    if (t < 128) dg[t] = rsqrtf(fmaxf(ps[2*t] + ps[2*t+1], 1.0f));
    __syncthreads();
    unsigned short* dst = pass ? A2b : A1b;
    for (int idx = t; idx < 16384; idx += 256){
      int nn = idx >> 7, m = idx & 127;
      float v = dg[nn] * As[nn*129 + m] * dg[m];
      if (!pass) As[nn*129 + m] = v;
      dst[b*16384 + idx] = f2bf(v);
    }
    __syncthreads();
  }
}

// S[b,t,n,f] = sum_v leaky(node[b,t,v,n,:]@Wn + bn)
__global__ __launch_bounds__(256) void k_nodeS(const float* __restrict__ inp,
                                               const float* __restrict__ Wn,
                                               const float* __restrict__ bn,
                                               float* __restrict__ S){
  __shared__ float WnL[80];
  __shared__ float bnL[16];
  int t = threadIdx.x;
  if (t < 80) WnL[t] = Wn[t];
  if (t < 16) bnL[t] = bn[t];
  __syncthreads();
  int id = blockIdx.x*256 + t;
  int b = id / 1280, rem = id % 1280;
  int tt = rem >> 7, n = rem & 127;
  float outv[16];
  #pragma unroll
  for (int f = 0; f < 16; ++f) outv[f] = 0.f;
  for (int v = 0; v < 3; ++v){
    const float* row = inp + (size_t)((b*30 + tt*3 + v)*128 + n)*389 + 384;
    float x0 = row[0], x1 = row[1], x2 = row[2], x3 = row[3], x4 = row[4];
    #pragma unroll
    for (int f = 0; f < 16; ++f){
      float a = bnL[f];
      a = fmaf(x0, WnL[f], a);
      a = fmaf(x1, WnL[16+f], a);
      a = fmaf(x2, WnL[32+f], a);
      a = fmaf(x3, WnL[48+f], a);
      a = fmaf(x4, WnL[64+f], a);
      outv[f] += LEAKY(a);
    }
  }
  float* dst = S + (size_t)((b*10 + tt)*128 + n)*16;
  #pragma unroll
  for (int q = 0; q < 4; ++q)
    *(float4*)(dst + q*4) = make_float4(outv[q*4], outv[q*4+1], outv[q*4+2], outv[q*4+3]);
}

// 2-layer GCN per (b,t): y = xs@Wg + 4*bgl ; z = leaky(A@y + gbias) ; MFMA bf16 propagate
__global__ __launch_bounds__(256) void k_gcn(const float* __restrict__ edge_enc,
                                             const float* __restrict__ S,
                                             const unsigned short* __restrict__ A1b,
                                             const unsigned short* __restrict__ A2b,
                                             const float* __restrict__ Wg,
                                             const float* __restrict__ bgl,
                                             const float* __restrict__ gbias,
                                             float* __restrict__ graph){
  __shared__ __align__(16) unsigned short Af[128*136];  // A matrix [n][m], bf16, stride 136
  __shared__ __align__(16) unsigned short YT[64*136];   // Y^T [io][m], bf16, stride 136
  __shared__ __align__(16) float xsb[128*16];           // xs, then reused as zsum (xs2)
  int blk = blockIdx.x;
  int b = blk/10, tt = blk%10;
  int t = threadIdx.x, lane = t & 63, wave = t >> 6;
  int io = lane, ic = io >> 4, o = io & 15;
  int lo = lane & 15, qd = lane >> 4;

  float wg0[16], wg1[16];
  #pragma unroll
  for (int f = 0; f < 16; ++f){
    wg0[f] = Wg[(ic*16 + f)*16 + o];
    wg1[f] = Wg[((4 + ic)*16 + f)*16 + o];
  }
  float bg0 = 4.f * bgl[ic*16 + o];
  float bg1 = 4.f * bgl[64 + ic*16 + o];
  float gb[4];
  #pragma unroll
  for (int q = 0; q < 4; ++q) gb[q] = gbias[q*16 + lo];

  // prefetch A1 (regs) while doing y-compute
  uint4 areg[8];
  {
    const uint4* gA = (const uint4*)(A1b + b*16384);
    #pragma unroll
    for (int q = 0; q < 8; ++q) areg[q] = gA[q*256 + t];
  }
  // stage xs = edge_enc + S
  {
    const float4* ge = (const float4*)(edge_enc + b*2048);
    const float4* gs = (const float4*)(S + (size_t)(b*10 + tt)*2048);
    float4* xf = (float4*)xsb;
    float4 a0 = ge[2*t], s0 = gs[2*t];
    float4 a1 = ge[2*t+1], s1 = gs[2*t+1];
    xf[2*t]   = make_float4(a0.x+s0.x, a0.y+s0.y, a0.z+s0.z, a0.w+s0.w);
    xf[2*t+1] = make_float4(a1.x+s1.x, a1.y+s1.y, a1.z+s1.z, a1.w+s1.w);
  }
  __syncthreads();

  // layer-0 y: all lanes of a wave share n (broadcast xs reads); write YT bf16
  #pragma unroll
  for (int nb = 0; nb < 32; nb += 8){
    unsigned pk[4];
    #pragma unroll
    for (int u = 0; u < 8; ++u){
      int n = wave*32 + nb + u;
      float a = dot16(&xsb[n*16], wg0, bg0);
      unsigned short hb = f2bf(a);
      if (u & 1) pk[u>>1] |= ((unsigned)hb) << 16; else pk[u>>1] = (unsigned)hb;
    }
    *(uint4*)&YT[io*136 + wave*32 + nb] = make_uint4(pk[0], pk[1], pk[2], pk[3]);
  }
  // write A1 into Af (padded rows)
  #pragma unroll
  for (int q = 0; q < 8; ++q){
    int c = q*256 + t;
    *(uint4*)&Af[(c >> 4)*136 + (c & 15)*8] = areg[q];
  }
  __syncthreads();

  // layer-0 MFMA: Z[128 x 64] = A1 @ Y
  f32x4 acc0[2][4];
  #pragma unroll
  for (int mi = 0; mi < 2; ++mi)
    #pragma unroll
    for (int nt = 0; nt < 4; ++nt) acc0[mi][nt] = (f32x4){0.f,0.f,0.f,0.f};
  #pragma unroll
  for (int kt = 0; kt < 4; ++kt){
    bf16x8 av[2], bv[4];
    #pragma unroll
    for (int mi = 0; mi < 2; ++mi)
      av[mi] = *(const bf16x8*)&Af[(wave*32 + mi*16 + lo)*136 + kt*32 + qd*8];
    #pragma unroll
    for (int nt = 0; nt < 4; ++nt)
      bv[nt] = *(const bf16x8*)&YT[(nt*16 + lo)*136 + kt*32 + qd*8];
    #pragma unroll
    for (int mi = 0; mi < 2; ++mi)
      #pragma unroll
      for (int nt = 0; nt < 4; ++nt)
        acc0[mi][nt] = __builtin_amdgcn_mfma_f32_16x16x32_bf16(av[mi], bv[nt], acc0[mi][nt], 0, 0, 0);
  }
  // prefetch A2
  {
    const uint4* gA = (const uint4*)(A2b + b*16384);
    #pragma unroll
    for (int q = 0; q < 8; ++q) areg[q] = gA[q*256 + t];
  }
  // epilogue-0: xs2[n][o] = sum_i leaky(z + gbias)   (each (n,o) owned by one lane)
  #pragma unroll
  for (int mi = 0; mi < 2; ++mi)
    #pragma unroll
    for (int r = 0; r < 4; ++r){
      float s = 0.f;
      #pragma unroll
      for (int nt = 0; nt < 4; ++nt){
        float v = acc0[mi][nt][r] + gb[nt];
        s += LEAKY(v);
      }
      int n = wave*32 + mi*16 + qd*4 + r;
      xsb[n*16 + lo] = s;
    }
  __syncthreads();

  // layer-1 y2 -> YT
  #pragma unroll
  for (int nb = 0; nb < 32; nb += 8){
    unsigned pk[4];
    #pragma unroll
    for (int u = 0; u < 8; ++u){
      int n = wave*32 + nb + u;
      float a = dot16(&xsb[n*16], wg1, bg1);
      unsigned short hb = f2bf(a);
      if (u & 1) pk[u>>1] |= ((unsigned)hb) << 16; else pk[u>>1] = (unsigned)hb;
    }
    *(uint4*)&YT[io*136 + wave*32 + nb] = make_uint4(pk[0], pk[1], pk[2], pk[3]);
  }
  // write A2 into Af
  #pragma unroll
  for (int q = 0; q < 8; ++q){
    int c = q*256 + t;
    *(uint4*)&Af[(c >> 4)*136 + (c & 15)*8] = areg[q];
  }
  __syncthreads();

  // layer-1 MFMA + accumulate into graph
  f32x4 acc1[2][4];
  #pragma unroll
  for (int mi = 0; mi < 2; ++mi)
    #pragma unroll
    for (int nt = 0; nt < 4; ++nt) acc1[mi][nt] = (f32x4){0.f,0.f,0.f,0.f};
  #pragma unroll
  for (int kt = 0; kt < 4; ++kt){
    bf16x8 av[2], bv[4];
    #pragma unroll
    for (int mi = 0; mi < 2; ++mi)
      av[mi] = *(const bf16x8*)&Af[(wave*32 + mi*16 + lo)*136 + kt*32 + qd*8];
    #pragma unroll
    for (int nt = 0; nt < 4; ++nt)
      bv[nt] = *(const bf16x8*)&YT[(nt*16 + lo)*136 + kt*32 + qd*8];
    #pragma unroll
    for (int mi = 0; mi < 2; ++mi)
      #pragma unroll
      for (int nt = 0; nt < 4; ++nt)
        acc1[mi][nt] = __builtin_amdgcn_mfma_f32_16x16x32_bf16(av[mi], bv[nt], acc1[mi][nt], 0, 0, 0);
  }
  float* gout = graph + (size_t)b*8192;
  #pragma unroll
  for (int mi = 0; mi < 2; ++mi)
    #pragma unroll
    for (int nt = 0; nt < 4; ++nt)
      #pragma unroll
      for (int r = 0; r < 4; ++r){
        float v = acc1[mi][nt][r] + gb[nt];
        v = LEAKY(v);
        int n = wave*32 + mi*16 + qd*4 + r;
        atomicAdd(&gout[nt*2048 + n*16 + lo], v);
      }
}

// big GEMM: (32 x 8192) @ (8192 x 4096 combined Wc1|Wa1), split-K=32 partials
__global__ __launch_bounds__(256) void k_gemm(const float* __restrict__ graph,
                                              const float* __restrict__ Wc1,
                                              const float* __restrict__ Wa1,
                                              float* __restrict__ part){
  __shared__ __align__(16) float flatc[32*256];
  __shared__ __align__(16) float Wt[16*256];
  int bx = blockIdx.x;
  int ks = bx >> 4, cb = bx & 15;
  const float* W = (cb < 8) ? Wc1 : Wa1;
  int cw0 = (cb & 7) * 256;
  int k0 = ks * 256;
  int t = threadIdx.x, lane = t & 63, wave = t >> 6;
  // stage flat chunk [32][256]
  #pragma unroll
  for (int q = 0; q < 8; ++q){
    int idx4 = t + 256*q; int r = idx4 >> 6, c4 = idx4 & 63;
    *(float4*)&flatc[r*256 + c4*4] = *(const float4*)(graph + (size_t)r*8192 + k0 + c4*4);
  }
  float4 acc4[8];
  #pragma unroll
  for (int i = 0; i < 8; ++i) acc4[i] = make_float4(0.f,0.f,0.f,0.f);
  float4 stg[4];
  #pragma unroll
  for (int q = 0; q < 4; ++q){
    int idx4 = t + 256*q; int s = idx4 >> 6, c4 = idx4 & 63;
    stg[q] = *(const float4*)(W + (size_t)(k0 + s)*2048 + cw0 + c4*4);
  }
  int r0 = wave*8, c0l = lane*4;
  for (int j = 0; j < 16; ++j){
    // LDS-only drain + barrier: keeps prefetched global loads in flight
    asm volatile("s_waitcnt lgkmcnt(0)\ns_barrier" ::: "memory");
    #pragma unroll
    for (int q = 0; q < 4; ++q){
      int idx4 = t + 256*q; int s = idx4 >> 6, c4 = idx4 & 63;
      *(float4*)&Wt[s*256 + c4*4] = stg[q];
    }
    if (j < 15){
      #pragma unroll
      for (int q = 0; q < 4; ++q){
        int idx4 = t + 256*q; int s = idx4 >> 6, c4 = idx4 & 63;
        stg[q] = *(const float4*)(W + (size_t)(k0 + (j+1)*16 + s)*2048 + cw0 + c4*4);
      }
    }
    asm volatile("s_waitcnt lgkmcnt(0)\ns_barrier" ::: "memory");
    #pragma unroll
    for (int kk4 = 0; kk4 < 4; ++kk4){
      float4 wv0 = *(const float4*)&Wt[(kk4*4+0)*256 + c0l];
      float4 wv1 = *(const float4*)&Wt[(kk4*4+1)*256 + c0l];
      float4 wv2 = *(const float4*)&Wt[(kk4*4+2)*256 + c0l];
      float4 wv3 = *(const float4*)&Wt[(kk4*4+3)*256 + c0l];
      #pragma unroll
      for (int ii = 0; ii < 8; ++ii){
        float4 fvv = *(const float4*)&flatc[(r0+ii)*256 + j*16 + kk4*4]; // broadcast
        fma4(acc4[ii], fvv.x, wv0);
        fma4(acc4[ii], fvv.y, wv1);
        fma4(acc4[ii], fvv.z, wv2);
        fma4(acc4[ii], fvv.w, wv3);
      }
    }
  }
  float* dst = part + (size_t)ks*131072 + cb*256 + c0l;
  #pragma unroll
  for (int ii = 0; ii < 8; ++ii)
    *(float4*)(dst + (size_t)(r0+ii)*4096) = acc4[ii];
}

__global__ __launch_bounds__(256) void k_reduce(const float* __restrict__ part,
                                                const float* __restrict__ bc1,
                                                const float* __restrict__ ba1,
                                                float* __restrict__ hcomb){
  int id = blockIdx.x*256 + threadIdx.x;
  float s = 0.f;
  #pragma unroll 8
  for (int p = 0; p < 32; ++p) s += part[(size_t)p*131072 + id];
  int c = id & 4095;
  s += (c < 2048) ? bc1[c] : ba1[c - 2048];
  hcomb[id] = LEAKY(s);
}

__global__ __launch_bounds__(256) void k_heads(const float* __restrict__ hcomb,
                                               const float* __restrict__ Wc2,
                                               const float* __restrict__ bc2,
                                               const float* __restrict__ Wc3,
                                               const float* __restrict__ bc3,
                                               const float* __restrict__ Wa2,
                                               const float* __restrict__ ba2,
                                               float* __restrict__ out){
  __shared__ float red[256*17];
  int r = blockIdx.x >> 1, which = blockIdx.x & 1;
  int t = threadIdx.x;
  const float* x = hcomb + r*4096 + which*2048;
  const float* W2 = which ? Wa2 : Wc2;
  float acc[16];
  #pragma unroll
  for (int f = 0; f < 16; ++f) acc[f] = 0.f;
  for (int k = t; k < 2048; k += 256){
    float xv = x[k];
    const float4* wr = (const float4*)(W2 + k*16);
    float4 w0 = wr[0], w1 = wr[1], w2 = wr[2], w3 = wr[3];
    acc[0]  = fmaf(xv, w0.x, acc[0]);  acc[1]  = fmaf(xv, w0.y, acc[1]);
    acc[2]  = fmaf(xv, w0.z, acc[2]);  acc[3]  = fmaf(xv, w0.w, acc[3]);
    acc[4]  = fmaf(xv, w1.x, acc[4]);  acc[5]  = fmaf(xv, w1.y, acc[5]);
    acc[6]  = fmaf(xv, w1.z, acc[6]);  acc[7]  = fmaf(xv, w1.w, acc[7]);
    acc[8]  = fmaf(xv, w2.x, acc[8]);  acc[9]  = fmaf(xv, w2.y, acc[9]);
    acc[10] = fmaf(xv, w2.z, acc[10]); acc[11] = fmaf(xv, w2.w, acc[11]);
    acc[12] = fmaf(xv, w3.x, acc[12]); acc[13] = fmaf(xv, w3.y, acc[13]);
    acc[14] = fmaf(xv, w3.z, acc[14]); acc[15] = fmaf(xv, w3.w, acc[15]);
  }
  #pragma unroll
  for (int f = 0; f < 16; ++f) red[t*17 + f] = acc[f];
  __syncthreads();
  for (int off = 128; off >= 1; off >>= 1){
    if (t < off){
      #pragma unroll
      for (int f = 0; f < 16; ++f) red[t*17 + f] += red[(t+off)*17 + f];
    }
    __syncthreads();
  }
  if (which == 0){
    if (t == 0){
      float c = bc3[0];
      #pragma unroll
      for (int f = 0; f < 16; ++f){
        float v = red[f] + bc2[f];
        v = LEAKY(v);
        c = fmaf(v, Wc3[f], c);
      }
      out[r] = c;
    }
  } else {
    if (t < 16){
      float v = red[t] + ba2[t];
      out[32 + r*16 + t] = LEAKY(v);
    }
  }
}

// workspace byte offsets
static const size_t O_EDGE  = 0;         //  262144 B : edge_enc 32x128x16 f32
static const size_t O_S     = 262144;    // 2621440 B : S 32x10x128x16 f32
static const size_t O_A1    = 2883584;   // 1048576 B : A1 bf16 32x128x128
static const size_t O_A2    = 3932160;   // 1048576 B : A2 bf16
static const size_t O_GRAPH = 4980736;   // 1048576 B : graph 32x4x128x16 f32
static const size_t O_PART  = 6029312;   // 16777216 B: partials 32x32x4096 f32
static const size_t O_HC    = 22806528;  //  524288 B : hcomb 32x4096 f32

extern "C" void kernel_launch(void* const* d_in, const int* in_sizes, int n_in,
                              void* d_out, int out_size, void* d_ws, size_t ws_size,
                              hipStream_t stream){
  const float* inp  = (const float*)d_in[0];
  const float* We   = (const float*)d_in[1];
  const float* be   = (const float*)d_in[2];
  const float* Wn   = (const float*)d_in[3];
  const float* bn   = (const float*)d_in[4];
  const float* Wg   = (const float*)d_in[5];
  const float* bgl  = (const float*)d_in[6];
  const float* gbias= (const float*)d_in[7];
  const float* Wc1  = (const float*)d_in[8];
  const float* bc1  = (const float*)d_in[9];
  const float* Wc2  = (const float*)d_in[10];
  const float* bc2  = (const float*)d_in[11];
  const float* Wc3  = (const float*)d_in[12];
  const float* bc3  = (const float*)d_in[13];
  const float* Wa1  = (const float*)d_in[14];
  const float* ba1  = (const float*)d_in[15];
  const float* Wa2  = (const float*)d_in[16];
  const float* ba2  = (const float*)d_in[17];

  char* ws = (char*)d_ws;
  float* edge_enc      = (float*)(ws + O_EDGE);
  float* S             = (float*)(ws + O_S);
  unsigned short* A1b  = (unsigned short*)(ws + O_A1);
  unsigned short* A2b  = (unsigned short*)(ws + O_A2);
  float* graph         = (float*)(ws + O_GRAPH);
  float* part          = (float*)(ws + O_PART);
  float* hcomb         = (float*)(ws + O_HC);

  hipMemsetAsync(graph, 0, 262144*sizeof(float), stream);
  hipLaunchKernelGGL(k_edge,   dim3(256), dim3(256), 0, stream, inp, We, be, edge_enc);
  hipLaunchKernelGGL(k_prep,   dim3(32),  dim3(256), 0, stream, inp, A1b, A2b);
  hipLaunchKernelGGL(k_nodeS,  dim3(160), dim3(256), 0, stream, inp, Wn, bn, S);
  hipLaunchKernelGGL(k_gcn,    dim3(320), dim3(256), 0, stream, edge_enc, S, A1b, A2b, Wg, bgl, gbias, graph);
  hipLaunchKernelGGL(k_gemm,   dim3(512), dim3(256), 0, stream, graph, Wc1, Wa1, part);
  hipLaunchKernelGGL(k_reduce, dim3(512), dim3(256), 0, stream, part, bc1, ba1, hcomb);
  hipLaunchKernelGGL(k_heads,  dim3(64),  dim3(256), 0, stream, hcomb, Wc2, bc2, Wc3, bc3, Wa2, ba2, (float*)d_out);
}

// Round 2
// 403.616 us; speedup vs baseline: 1.0142x; 1.0142x over previous
//
#include <hip/hip_runtime.h>
#include <stdint.h>

#define LEAKY(x) ((x) > 0.f ? (x) : 0.01f*(x))

typedef __attribute__((ext_vector_type(8))) short bf16x8;
typedef __attribute__((ext_vector_type(4))) float f32x4;

__device__ __forceinline__ unsigned short f2bf(float x){
  unsigned u = __float_as_uint(x);
  u += 0x7FFFu + ((u >> 16) & 1u);
  return (unsigned short)(u >> 16);
}
__device__ __forceinline__ void fma4(float4& a, float s, const float4& w){
  a.x = fmaf(s, w.x, a.x); a.y = fmaf(s, w.y, a.y);
  a.z = fmaf(s, w.z, a.z); a.w = fmaf(s, w.w, a.w);
}
__device__ __forceinline__ float dot16(const float* __restrict__ xn, const float* wg, float a){
  float4 x0 = *(const float4*)(xn);
  float4 x1 = *(const float4*)(xn+4);
  float4 x2 = *(const float4*)(xn+8);
  float4 x3 = *(const float4*)(xn+12);
  a = fmaf(x0.x, wg[0], a);  a = fmaf(x0.y, wg[1], a);  a = fmaf(x0.z, wg[2], a);  a = fmaf(x0.w, wg[3], a);
  a = fmaf(x1.x, wg[4], a);  a = fmaf(x1.y, wg[5], a);  a = fmaf(x1.z, wg[6], a);  a = fmaf(x1.w, wg[7], a);
  a = fmaf(x2.x, wg[8], a);  a = fmaf(x2.y, wg[9], a);  a = fmaf(x2.z, wg[10], a); a = fmaf(x2.w, wg[11], a);
  a = fmaf(x3.x, wg[12], a); a = fmaf(x3.y, wg[13], a); a = fmaf(x3.z, wg[14], a); a = fmaf(x3.w, wg[15], a);
  return a;
}

// Fused stage-1: blocks [0,256) edge-enc, [256,288) adjacency prep, [288,448) node-enc.
// One kernel so the three independent latency-bound phases overlap on the CUs.
__global__ __launch_bounds__(256) void k_stage1(const float* __restrict__ inp,
                                                const float* __restrict__ We,
                                                const float* __restrict__ be,
                                                const float* __restrict__ Wn,
                                                const float* __restrict__ bn,
                                                float* __restrict__ edge_enc,
                                                unsigned short* __restrict__ A1b,
                                                unsigned short* __restrict__ A2b,
                                                float* __restrict__ S){
  __shared__ float sm[16896];   // 66 KB: prep's As[128*129] + ps[256] + dg[128]
  int bx = blockIdx.x, t = threadIdx.x;

  if (bx < 256){
    // edge_enc[b,j,f] = sum_i leaky(edge[b,i,j,:]@We + be) * adj[b,i,j]
    int b = bx >> 3, jg = bx & 7;
    int j = jg*16 + (t >> 4), f = t & 15;
    const float* base = inp + (size_t)b*30*128*389;
    float w0 = We[f], w1 = We[16+f], bf = be[f];
    float acc = 0.f;
    #pragma unroll 4
    for (int i = 0; i < 128; ++i){
      const float* row = base + i*389;
      float adjv = row[j];
      float2 e = *(const float2*)(row + 128 + 2*j);
      float v = fmaf(e.x, w0, fmaf(e.y, w1, bf));
      v = LEAKY(v);
      acc = fmaf(v, adjv, acc);
    }
    edge_enc[b*2048 + j*16 + f] = acc;
  } else if (bx < 288){
    // adjacency: diag=1, two rounds of symmetric degree normalization -> bf16 A1,A2
    float* As = sm; float* ps = sm + 16512; float* dg = sm + 16768;
    int b = bx - 256;
    const float* base = inp + (size_t)b*30*128*389;
    for (int idx = t; idx < 16384; idx += 256){
      int n = idx >> 7, m = idx & 127;
      As[n*129 + m] = base[n*389 + m];
    }
    __syncthreads();
    if (t < 128) As[t*129 + t] = 1.0f;
    __syncthreads();
    for (int pass = 0; pass < 2; ++pass){
      int n = t >> 1, h = t & 1;
      float s = 0.f;
      for (int m = h*64; m < h*64 + 64; ++m) s += As[n*129 + m];
      ps[t] = s;
      __syncthreads();
      if (t < 128) dg[t] = rsqrtf(fmaxf(ps[2*t] + ps[2*t+1], 1.0f));
      __syncthreads();
      unsigned short* dst = pass ? A2b : A1b;
      for (int idx = t; idx < 16384; idx += 256){
        int nn = idx >> 7, m = idx & 127;
        float v = dg[nn] * As[nn*129 + m] * dg[m];
        if (!pass) As[nn*129 + m] = v;
        dst[b*16384 + idx] = f2bf(v);
      }
      __syncthreads();
    }
  } else {
    // S[b,t,n,f] = sum_v leaky(node[b,t,v,n,:]@Wn + bn)
    float* WnL = sm; float* bnL = sm + 80;
    if (t < 80) WnL[t] = Wn[t];
    if (t < 16) bnL[t] = bn[t];
    __syncthreads();
    int id = (bx - 288)*256 + t;
    int b = id / 1280, rem = id % 1280;
    int tt = rem >> 7, n = rem & 127;
    float outv[16];
    #pragma unroll
    for (int f = 0; f < 16; ++f) outv[f] = 0.f;
    for (int v = 0; v < 3; ++v){
      const float* row = inp + (size_t)((b*30 + tt*3 + v)*128 + n)*389 + 384;
      float x0 = row[0], x1 = row[1], x2 = row[2], x3 = row[3], x4 = row[4];
      #pragma unroll
      for (int f = 0; f < 16; ++f){
        float a = bnL[f];
        a = fmaf(x0, WnL[f], a);
        a = fmaf(x1, WnL[16+f], a);
        a = fmaf(x2, WnL[32+f], a);
        a = fmaf(x3, WnL[48+f], a);
        a = fmaf(x4, WnL[64+f], a);
        outv[f] += LEAKY(a);
      }
    }
    float* dst = S + (size_t)((b*10 + tt)*128 + n)*16;
    #pragma unroll
    for (int q = 0; q < 4; ++q)
      *(float4*)(dst + q*4) = make_float4(outv[q*4], outv[q*4+1], outv[q*4+2], outv[q*4+3]);
  }
}

// 2-layer GCN per (b,t): y = xs@Wg + 4*bgl ; z = leaky(A@y + gbias) ; MFMA bf16 propagate.
// Writes non-atomic per-(b,tt) slice g10; k_sum reduces over tt.
__global__ __launch_bounds__(256) void k_gcn(const float* __restrict__ edge_enc,
                                             const float* __restrict__ S,
                                             const unsigned short* __restrict__ A1b,
                                             const unsigned short* __restrict__ A2b,
                                             const float* __restrict__ Wg,
                                             const float* __restrict__ bgl,
                                             const float* __restrict__ gbias,
                                             float* __restrict__ g10){
  __shared__ __align__(16) unsigned short Af[128*136];  // A [n][m] bf16, stride 136
  __shared__ __align__(16) unsigned short YT[64*136];   // Y^T [io][m] bf16, stride 136
  __shared__ __align__(16) float xsb[128*16];
  int blk = blockIdx.x;
  int b = blk/10, tt = blk%10;
  int t = threadIdx.x, lane = t & 63, wave = t >> 6;
  int io = lane, ic = io >> 4, o = io & 15;
  int lo = lane & 15, qd = lane >> 4;

  float wg0[16], wg1[16];
  #pragma unroll
  for (int f = 0; f < 16; ++f){
    wg0[f] = Wg[(ic*16 + f)*16 + o];
    wg1[f] = Wg[((4 + ic)*16 + f)*16 + o];
  }
  float bg0 = 4.f * bgl[ic*16 + o];
  float bg1 = 4.f * bgl[64 + ic*16 + o];
  float gb[4];
  #pragma unroll
  for (int q = 0; q < 4; ++q) gb[q] = gbias[q*16 + lo];

  uint4 areg[8];
  {
    const uint4* gA = (const uint4*)(A1b + b*16384);
    #pragma unroll
    for (int q = 0; q < 8; ++q) areg[q] = gA[q*256 + t];
  }
  {
    const float4* ge = (const float4*)(edge_enc + b*2048);
    const float4* gs = (const float4*)(S + (size_t)(b*10 + tt)*2048);
    float4* xf = (float4*)xsb;
    float4 a0 = ge[2*t], s0 = gs[2*t];
    float4 a1 = ge[2*t+1], s1 = gs[2*t+1];
    xf[2*t]   = make_float4(a0.x+s0.x, a0.y+s0.y, a0.z+s0.z, a0.w+s0.w);
    xf[2*t+1] = make_float4(a1.x+s1.x, a1.y+s1.y, a1.z+s1.z, a1.w+s1.w);
  }
  __syncthreads();

  #pragma unroll
  for (int nb = 0; nb < 32; nb += 8){
    unsigned pk[4];
    #pragma unroll
    for (int u = 0; u < 8; ++u){
      int n = wave*32 + nb + u;
      float a = dot16(&xsb[n*16], wg0, bg0);
      unsigned short hb = f2bf(a);
      if (u & 1) pk[u>>1] |= ((unsigned)hb) << 16; else pk[u>>1] = (unsigned)hb;
    }
    *(uint4*)&YT[io*136 + wave*32 + nb] = make_uint4(pk[0], pk[1], pk[2], pk[3]);
  }
  #pragma unroll
  for (int q = 0; q < 8; ++q){
    int c = q*256 + t;
    *(uint4*)&Af[(c >> 4)*136 + (c & 15)*8] = areg[q];
  }
  __syncthreads();

  f32x4 acc0[2][4];
  #pragma unroll
  for (int mi = 0; mi < 2; ++mi)
    #pragma unroll
    for (int nt = 0; nt < 4; ++nt) acc0[mi][nt] = (f32x4){0.f,0.f,0.f,0.f};
  #pragma unroll
  for (int kt = 0; kt < 4; ++kt){
    bf16x8 av[2], bv[4];
    #pragma unroll
    for (int mi = 0; mi < 2; ++mi)
      av[mi] = *(const bf16x8*)&Af[(wave*32 + mi*16 + lo)*136 + kt*32 + qd*8];
    #pragma unroll
    for (int nt = 0; nt < 4; ++nt)
      bv[nt] = *(const bf16x8*)&YT[(nt*16 + lo)*136 + kt*32 + qd*8];
    #pragma unroll
    for (int mi = 0; mi < 2; ++mi)
      #pragma unroll
      for (int nt = 0; nt < 4; ++nt)
        acc0[mi][nt] = __builtin_amdgcn_mfma_f32_16x16x32_bf16(av[mi], bv[nt], acc0[mi][nt], 0, 0, 0);
  }
  {
    const uint4* gA = (const uint4*)(A2b + b*16384);
    #pragma unroll
    for (int q = 0; q < 8; ++q) areg[q] = gA[q*256 + t];
  }
  #pragma unroll
  for (int mi = 0; mi < 2; ++mi)
    #pragma unroll
    for (int r = 0; r < 4; ++r){
      float s = 0.f;
      #pragma unroll
      for (int nt = 0; nt < 4; ++nt){
        float v = acc0[mi][nt][r] + gb[nt];
        s += LEAKY(v);
      }
      int n = wave*32 + mi*16 + qd*4 + r;
      xsb[n*16 + lo] = s;
    }
  __syncthreads();

  #pragma unroll
  for (int nb = 0; nb < 32; nb += 8){
    unsigned pk[4];
    #pragma unroll
    for (int u = 0; u < 8; ++u){
      int n = wave*32 + nb + u;
      float a = dot16(&xsb[n*16], wg1, bg1);
      unsigned short hb = f2bf(a);
      if (u & 1) pk[u>>1] |= ((unsigned)hb) << 16; else pk[u>>1] = (unsigned)hb;
    }
    *(uint4*)&YT[io*136 + wave*32 + nb] = make_uint4(pk[0], pk[1], pk[2], pk[3]);
  }
  #pragma unroll
  for (int q = 0; q < 8; ++q){
    int c = q*256 + t;
    *(uint4*)&Af[(c >> 4)*136 + (c & 15)*8] = areg[q];
  }
  __syncthreads();

  f32x4 acc1[2][4];
  #pragma unroll
  for (int mi = 0; mi < 2; ++mi)
    #pragma unroll
    for (int nt = 0; nt < 4; ++nt) acc1[mi][nt] = (f32x4){0.f,0.f,0.f,0.f};
  #pragma unroll
  for (int kt = 0; kt < 4; ++kt){
    bf16x8 av[2], bv[4];
    #pragma unroll
    for (int mi = 0; mi < 2; ++mi)
      av[mi] = *(const bf16x8*)&Af[(wave*32 + mi*16 + lo)*136 + kt*32 + qd*8];
    #pragma unroll
    for (int nt = 0; nt < 4; ++nt)
      bv[nt] = *(const bf16x8*)&YT[(nt*16 + lo)*136 + kt*32 + qd*8];
    #pragma unroll
    for (int mi = 0; mi < 2; ++mi)
      #pragma unroll
      for (int nt = 0; nt < 4; ++nt)
        acc1[mi][nt] = __builtin_amdgcn_mfma_f32_16x16x32_bf16(av[mi], bv[nt], acc1[mi][nt], 0, 0, 0);
  }
  float* gout = g10 + (size_t)(b*10 + tt)*8192;
  #pragma unroll
  for (int mi = 0; mi < 2; ++mi)
    #pragma unroll
    for (int nt = 0; nt < 4; ++nt)
      #pragma unroll
      for (int r = 0; r < 4; ++r){
        float v = acc1[mi][nt][r] + gb[nt];
        v = LEAKY(v);
        int n = wave*32 + mi*16 + qd*4 + r;
        gout[nt*2048 + n*16 + lo] = v;
      }
}

// graph[b, :] = sum_tt g10[b,tt,:]   (deterministic, replaces atomics)
__global__ __launch_bounds__(256) void k_sum(const float* __restrict__ g10,
                                             float* __restrict__ graph){
  int blk = blockIdx.x;
  int b = blk >> 3, seg = blk & 7;
  int t = threadIdx.x;
  size_t off = (size_t)seg*1024 + t*4;
  float4 a = make_float4(0.f,0.f,0.f,0.f);
  #pragma unroll
  for (int tt = 0; tt < 10; ++tt){
    float4 v = *(const float4*)(g10 + (size_t)(b*10 + tt)*8192 + off);
    a.x += v.x; a.y += v.y; a.z += v.z; a.w += v.w;
  }
  *(float4*)(graph + (size_t)b*8192 + off) = a;
}

// big GEMM: (32 x 8192) @ (8192 x 4096 combined Wc1|Wa1), split-K=32 partials
__global__ __launch_bounds__(256) void k_gemm(const float* __restrict__ graph,
                                              const float* __restrict__ Wc1,
                                              const float* __restrict__ Wa1,
                                              float* __restrict__ part){
  __shared__ __align__(16) float flatc[32*256];
  __shared__ __align__(16) float Wt[16*256];
  int bx = blockIdx.x;
  int ks = bx >> 4, cb = bx & 15;
  const float* W = (cb < 8) ? Wc1 : Wa1;
  int cw0 = (cb & 7) * 256;
  int k0 = ks * 256;
  int t = threadIdx.x, lane = t & 63, wave = t >> 6;
  #pragma unroll
  for (int q = 0; q < 8; ++q){
    int idx4 = t + 256*q; int r = idx4 >> 6, c4 = idx4 & 63;
    *(float4*)&flatc[r*256 + c4*4] = *(const float4*)(graph + (size_t)r*8192 + k0 + c4*4);
  }
  float4 acc4[8];
  #pragma unroll
  for (int i = 0; i < 8; ++i) acc4[i] = make_float4(0.f,0.f,0.f,0.f);
  float4 stg[4];
  #pragma unroll
  for (int q = 0; q < 4; ++q){
    int idx4 = t + 256*q; int s = idx4 >> 6, c4 = idx4 & 63;
    stg[q] = *(const float4*)(W + (size_t)(k0 + s)*2048 + cw0 + c4*4);
  }
  int r0 = wave*8, c0l = lane*4;
  for (int j = 0; j < 16; ++j){
    asm volatile("s_waitcnt lgkmcnt(0)\ns_barrier" ::: "memory");
    #pragma unroll
    for (int q = 0; q < 4; ++q){
      int idx4 = t + 256*q; int s = idx4 >> 6, c4 = idx4 & 63;
      *(float4*)&Wt[s*256 + c4*4] = stg[q];
    }
    if (j < 15){
      #pragma unroll
      for (int q = 0; q < 4; ++q){
        int idx4 = t + 256*q; int s = idx4 >> 6, c4 = idx4 & 63;
        stg[q] = *(const float4*)(W + (size_t)(k0 + (j+1)*16 + s)*2048 + cw0 + c4*4);
      }
    }
    asm volatile("s_waitcnt lgkmcnt(0)\ns_barrier" ::: "memory");
    #pragma unroll
    for (int kk4 = 0; kk4 < 4; ++kk4){
      float4 wv0 = *(const float4*)&Wt[(kk4*4+0)*256 + c0l];
      float4 wv1 = *(const float4*)&Wt[(kk4*4+1)*256 + c0l];
      float4 wv2 = *(const float4*)&Wt[(kk4*4+2)*256 + c0l];
      float4 wv3 = *(const float4*)&Wt[(kk4*4+3)*256 + c0l];
      #pragma unroll
      for (int ii = 0; ii < 8; ++ii){
        float4 fvv = *(const float4*)&flatc[(r0+ii)*256 + j*16 + kk4*4]; // broadcast
        fma4(acc4[ii], fvv.x, wv0);
        fma4(acc4[ii], fvv.y, wv1);
        fma4(acc4[ii], fvv.z, wv2);
        fma4(acc4[ii], fvv.w, wv3);
      }
    }
  }
  float* dst = part + (size_t)ks*131072 + cb*256 + c0l;
  #pragma unroll
  for (int ii = 0; ii < 8; ++ii)
    *(float4*)(dst + (size_t)(r0+ii)*4096) = acc4[ii];
}

// heads with folded split-K reduce: xv = leaky(sum_p part + b1), then W2/W3 heads
__global__ __launch_bounds__(256) void k_heads(const float* __restrict__ part,
                                               const float* __restrict__ bc1,
                                               const float* __restrict__ ba1,
                                               const float* __restrict__ Wc2,
                                               const float* __restrict__ bc2,
                                               const float* __restrict__ Wc3,
                                               const float* __restrict__ bc3,
                                               const float* __restrict__ Wa2,
                                               const float* __restrict__ ba2,
                                               float* __restrict__ out){
  __shared__ float red[256*17];
  int r = blockIdx.x >> 1, which = blockIdx.x & 1;
  int t = threadIdx.x;
  const float* W2 = which ? Wa2 : Wc2;
  const float* b1 = which ? ba1 : bc1;
  const float* pbase = part + (size_t)r*4096 + which*2048;
  float acc[16];
  #pragma unroll
  for (int f = 0; f < 16; ++f) acc[f] = 0.f;
  for (int k = t; k < 2048; k += 256){
    float s = 0.f;
    #pragma unroll 8
    for (int p = 0; p < 32; ++p) s += pbase[(size_t)p*131072 + k];
    s += b1[k];
    float xv = LEAKY(s);
    const float4* wr = (const float4*)(W2 + k*16);
    float4 w0 = wr[0], w1 = wr[1], w2 = wr[2], w3 = wr[3];
    acc[0]  = fmaf(xv, w0.x, acc[0]);  acc[1]  = fmaf(xv, w0.y, acc[1]);
    acc[2]  = fmaf(xv, w0.z, acc[2]);  acc[3]  = fmaf(xv, w0.w, acc[3]);
    acc[4]  = fmaf(xv, w1.x, acc[4]);  acc[5]  = fmaf(xv, w1.y, acc[5]);
    acc[6]  = fmaf(xv, w1.z, acc[6]);  acc[7]  = fmaf(xv, w1.w, acc[7]);
    acc[8]  = fmaf(xv, w2.x, acc[8]);  acc[9]  = fmaf(xv, w2.y, acc[9]);
    acc[10] = fmaf(xv, w2.z, acc[10]); acc[11] = fmaf(xv, w2.w, acc[11]);
    acc[12] = fmaf(xv, w3.x, acc[12]); acc[13] = fmaf(xv, w3.y, acc[13]);
    acc[14] = fmaf(xv, w3.z, acc[14]); acc[15] = fmaf(xv, w3.w, acc[15]);
  }
  #pragma unroll
  for (int f = 0; f < 16; ++f) red[t*17 + f] = acc[f];
  __syncthreads();
  for (int off = 128; off >= 1; off >>= 1){
    if (t < off){
      #pragma unroll
      for (int f = 0; f < 16; ++f) red[t*17 + f] += red[(t+off)*17 + f];
    }
    __syncthreads();
  }
  if (which == 0){
    if (t == 0){
      float c = bc3[0];
      #pragma unroll
      for (int f = 0; f < 16; ++f){
        float v = red[f] + bc2[f];
        v = LEAKY(v);
        c = fmaf(v, Wc3[f], c);
      }
      out[r] = c;
    }
  } else {
    if (t < 16){
      float v = red[t] + ba2[t];
      out[32 + r*16 + t] = LEAKY(v);
    }
  }
}

// workspace byte offsets
static const size_t O_EDGE  = 0;          //  262144 B : edge_enc 32x128x16 f32
static const size_t O_S     = 262144;     // 2621440 B : S 32x10x128x16 f32
static const size_t O_A1    = 2883584;    // 1048576 B : A1 bf16
static const size_t O_A2    = 3932160;    // 1048576 B : A2 bf16
static const size_t O_G10   = 4980736;    // 10485760 B: g10 32x10x8192 f32
static const size_t O_GRAPH = 15466496;   // 1048576 B : graph 32x8192 f32
static const size_t O_PART  = 16515072;   // 16777216 B: partials 32x32x4096 f32

extern "C" void kernel_launch(void* const* d_in, const int* in_sizes, int n_in,
                              void* d_out, int out_size, void* d_ws, size_t ws_size,
                              hipStream_t stream){
  const float* inp  = (const float*)d_in[0];
  const float* We   = (const float*)d_in[1];
  const float* be   = (const float*)d_in[2];
  const float* Wn   = (const float*)d_in[3];
  const float* bn   = (const float*)d_in[4];
  const float* Wg   = (const float*)d_in[5];
  const float* bgl  = (const float*)d_in[6];
  const float* gbias= (const float*)d_in[7];
  const float* Wc1  = (const float*)d_in[8];
  const float* bc1  = (const float*)d_in[9];
  const float* Wc2  = (const float*)d_in[10];
  const float* bc2  = (const float*)d_in[11];
  const float* Wc3  = (const float*)d_in[12];
  const float* bc3  = (const float*)d_in[13];
  const float* Wa1  = (const float*)d_in[14];
  const float* ba1  = (const float*)d_in[15];
  const float* Wa2  = (const float*)d_in[16];
  const float* ba2  = (const float*)d_in[17];

  char* ws = (char*)d_ws;
  float* edge_enc      = (float*)(ws + O_EDGE);
  float* S             = (float*)(ws + O_S);
  unsigned short* A1b  = (unsigned short*)(ws + O_A1);
  unsigned short* A2b  = (unsigned short*)(ws + O_A2);
  float* g10           = (float*)(ws + O_G10);
  float* graph         = (float*)(ws + O_GRAPH);
  float* part          = (float*)(ws + O_PART);

  hipLaunchKernelGGL(k_stage1, dim3(448), dim3(256), 0, stream, inp, We, be, Wn, bn, edge_enc, A1b, A2b, S);
  hipLaunchKernelGGL(k_gcn,    dim3(320), dim3(256), 0, stream, edge_enc, S, A1b, A2b, Wg, bgl, gbias, g10);
  hipLaunchKernelGGL(k_sum,    dim3(256), dim3(256), 0, stream, g10, graph);
  hipLaunchKernelGGL(k_gemm,   dim3(512), dim3(256), 0, stream, graph, Wc1, Wa1, part);
  hipLaunchKernelGGL(k_heads,  dim3(64),  dim3(256), 0, stream, part, bc1, ba1, Wc2, bc2, Wc3, bc3, Wa2, ba2, (float*)d_out);
}